// Round 1
// baseline (430.040 us; speedup 1.0000x reference)
//
#include <hip/hip_runtime.h>
#include <hip/hip_bf16.h>
#include <math.h>

#define BATCH 8192
#define INSZ 784
#define SYS 1024
#define OUTSZ 10
#define NSTEP 100
#define HSTEP 0.01f
#define FFORCE 8.0f
#define KP 800   // 25*32: K padded for pre-split arrays (784..799 zero-filled)

typedef short short8 __attribute__((ext_vector_type(8)));
typedef float float4v __attribute__((ext_vector_type(4)));
typedef float v2f __attribute__((ext_vector_type(2)));

static __device__ __forceinline__ short f2bf(float x) {
    __hip_bfloat16 b = __float2bfloat16(x);   // RNE
    return __builtin_bit_cast(short, b);
}
static __device__ __forceinline__ float bf2f(short s) {
    unsigned int u = ((unsigned int)(unsigned short)s) << 16;
    return __builtin_bit_cast(float, u);
}

static __device__ __forceinline__ v2f pkfma(v2f a, v2f b, v2f c) {
    return __builtin_elementwise_fma(a, b, c);
}
static __device__ __forceinline__ v2f mk2(float x, float y) {
    v2f r; r.x = x; r.y = y; return r;
}
// halo transport on the DS pipe (overlaps with VALU; DPP regressed — r5)
static __device__ __forceinline__ v2f sh2(v2f v, int ln) {
    v2f r; r.x = __shfl(v.x, ln); r.y = __shfl(v.y, ln); return r;
}

// ---------------------------------------------------------------------------
// convert_kernel: one-shot fp32 -> split-bf16 (hi + lo residual, RNE — bitwise
// identical to the in-gemm conversion it replaces). Writes K-padded [row][800]
// arrays so gemm1s needs no bounds checks. Memory-bound: ~58 MB, ~12-15 us.
// Rows 0..8191 = x, rows 8192..9215 = W1.
// ---------------------------------------------------------------------------
__global__ __launch_bounds__(256) void convert_kernel(
    const float* __restrict__ x, const float* __restrict__ W1,
    short* __restrict__ xh, short* __restrict__ xl,
    short* __restrict__ wh, short* __restrict__ wl)
{
    const int total = (BATCH + SYS) * (KP / 8);   // 921600 8-elem chunks
    for (int idx = blockIdx.x * blockDim.x + threadIdx.x; idx < total;
         idx += gridDim.x * blockDim.x) {
        const int row = idx / (KP / 8);
        const int ck  = idx - row * (KP / 8);

        short8 hi, lo;
        if (ck < INSZ / 8) {   // 784/8 = 98: all-or-nothing per chunk
            const float* src = (row < BATCH)
                ? (x + (size_t)row * INSZ)
                : (W1 + (size_t)(row - BATCH) * INSZ);
            float4 v0 = ((const float4*)src)[ck * 2];
            float4 v1 = ((const float4*)src)[ck * 2 + 1];
            float vv[8] = {v0.x, v0.y, v0.z, v0.w, v1.x, v1.y, v1.z, v1.w};
            #pragma unroll
            for (int j = 0; j < 8; ++j) {
                short hj = f2bf(vv[j]);
                hi[j] = hj;
                lo[j] = f2bf(vv[j] - bf2f(hj));
            }
        } else {
            #pragma unroll
            for (int j = 0; j < 8; ++j) { hi[j] = 0; lo[j] = 0; }
        }

        short* dh; short* dl;
        if (row < BATCH) {
            dh = xh + (size_t)row * KP;
            dl = xl + (size_t)row * KP;
        } else {
            dh = wh + (size_t)(row - BATCH) * KP;
            dl = wl + (size_t)(row - BATCH) * KP;
        }
        *(short8*)(dh + ck * 8) = hi;
        *(short8*)(dl + ck * 8) = lo;
    }
}

// ---------------------------------------------------------------------------
// GEMM1 (pre-split path): h = x @ W1^T + b1. Same 64x64 tile / BK=32 /
// 3-MFMA split-bf16 as before, but:
//  - operands arrive pre-split (no per-block cvt VALU work; W1 was being
//    re-converted 128x, x 16x in the old kernel)
//  - 2-phase register prefetch of next K-slab (global load hides under MFMA)
//  - 2x2 wave->fragment map (wave owns 32x32): 8 instead of 10 ds_read_b128
//    per wave-iter
// ---------------------------------------------------------------------------
#define BM2 64
#define BN2 64
#define BK2 32
#define LDK2 40   // shorts; 80 B row stride -> <=2-way bank alias (free, m136)

__global__ __launch_bounds__(256, 4) void gemm1s_kernel(
    const short* __restrict__ xh, const short* __restrict__ xl,
    const short* __restrict__ wh, const short* __restrict__ wl,
    const float* __restrict__ b1, float* __restrict__ h)
{
    __shared__ short Ah[BM2 * LDK2], Al[BM2 * LDK2];
    __shared__ short Bh[BN2 * LDK2], Bl[BN2 * LDK2];   // 4 * 5120 B = 20 KB

    const int t  = threadIdx.x;
    const int bm = blockIdx.y * BM2;
    const int bn = blockIdx.x * BN2;

    // staging role: 4 lanes per row, 8 contiguous shorts per lane
    const int srow = t >> 2;          // 0..63
    const int kq   = (t & 3) * 8;     // 0,8,16,24

    // compute role: 2x2 wave grid, each wave owns a 32x32 sub-tile
    const int wv   = t >> 6;
    const int wr   = wv >> 1;         // 0..1 row half
    const int wc   = wv & 1;          // 0..1 col half
    const int lane = t & 63;
    const int lm   = lane & 15;
    const int q    = lane >> 4;

    float4v acc[2][2];
    #pragma unroll
    for (int mi = 0; mi < 2; ++mi)
        #pragma unroll
        for (int nj = 0; nj < 2; ++nj) {
            acc[mi][nj][0] = 0.f; acc[mi][nj][1] = 0.f;
            acc[mi][nj][2] = 0.f; acc[mi][nj][3] = 0.f;
        }

    const short* pxh = xh + (size_t)(bm + srow) * KP + kq;
    const short* pxl = xl + (size_t)(bm + srow) * KP + kq;
    const short* pwh = wh + (size_t)(bn + srow) * KP + kq;
    const short* pwl = wl + (size_t)(bn + srow) * KP + kq;
    const int sbase = srow * LDK2 + kq;

    // prologue: K-slab 0 into registers
    short8 ra = *(const short8*)(pxh);
    short8 rb = *(const short8*)(pxl);
    short8 rc = *(const short8*)(pwh);
    short8 rd = *(const short8*)(pwl);

    for (int it = 0; it < 25; ++it) {
        *(short8*)&Ah[sbase] = ra;
        *(short8*)&Al[sbase] = rb;
        *(short8*)&Bh[sbase] = rc;
        *(short8*)&Bl[sbase] = rd;
        __syncthreads();

        if (it < 24) {   // issue next slab's loads; latency hides under MFMA
            const int k1 = (it + 1) * BK2;
            ra = *(const short8*)(pxh + k1);
            rb = *(const short8*)(pxl + k1);
            rc = *(const short8*)(pwh + k1);
            rd = *(const short8*)(pwl + k1);
        }

        short8 fah[2], fal[2], fbh[2], fbl[2];
        #pragma unroll
        for (int mi = 0; mi < 2; ++mi) {
            const int ao = (wr * 32 + mi * 16 + lm) * LDK2 + q * 8;
            fah[mi] = *(const short8*)&Ah[ao];
            fal[mi] = *(const short8*)&Al[ao];
        }
        #pragma unroll
        for (int nj = 0; nj < 2; ++nj) {
            const int bo = (wc * 32 + nj * 16 + lm) * LDK2 + q * 8;
            fbh[nj] = *(const short8*)&Bh[bo];
            fbl[nj] = *(const short8*)&Bl[bo];
        }
        #pragma unroll
        for (int mi = 0; mi < 2; ++mi)
            #pragma unroll
            for (int nj = 0; nj < 2; ++nj) {
                acc[mi][nj] = __builtin_amdgcn_mfma_f32_16x16x32_bf16(fah[mi], fbh[nj], acc[mi][nj], 0, 0, 0);
                acc[mi][nj] = __builtin_amdgcn_mfma_f32_16x16x32_bf16(fah[mi], fbl[nj], acc[mi][nj], 0, 0, 0);
                acc[mi][nj] = __builtin_amdgcn_mfma_f32_16x16x32_bf16(fal[mi], fbh[nj], acc[mi][nj], 0, 0, 0);
            }
        __syncthreads();
    }

    // epilogue: + b1, store fp32. C/D: col = lm, row = q*4 + r.
    #pragma unroll
    for (int mi = 0; mi < 2; ++mi) {
        const int row0 = bm + wr * 32 + mi * 16 + q * 4;
        #pragma unroll
        for (int nj = 0; nj < 2; ++nj) {
            const int col  = bn + wc * 32 + nj * 16 + lm;
            const float bias = b1[col];
            #pragma unroll
            for (int r = 0; r < 4; ++r)
                h[(size_t)(row0 + r) * SYS + col] = acc[mi][nj][r] + bias;
        }
    }
}

// ---------------------------------------------------------------------------
// GEMM1 fallback (old in-kernel conversion path) — used only if the provided
// workspace can't hold the pre-split arrays. Verbatim from previous version.
// ---------------------------------------------------------------------------
__global__ __launch_bounds__(256, 4) void gemm1_kernel(
    const float* __restrict__ x, const float* __restrict__ W1,
    const float* __restrict__ b1, float* __restrict__ h)
{
    __shared__ short Ah[BM2 * LDK2], Al[BM2 * LDK2];
    __shared__ short Bh[BN2 * LDK2], Bl[BN2 * LDK2];

    const int t  = threadIdx.x;
    const int bm = blockIdx.y * BM2;
    const int bn = blockIdx.x * BN2;

    const int srow = t >> 2;
    const int kq   = (t & 3) * 8;

    const int wv   = t >> 6;
    const int lane = t & 63;
    const int lm   = lane & 15;
    const int q    = lane >> 4;

    float4v acc[4];
    #pragma unroll
    for (int j = 0; j < 4; ++j) {
        acc[j][0] = 0.f; acc[j][1] = 0.f; acc[j][2] = 0.f; acc[j][3] = 0.f;
    }

    const float* xa0 = x  + (size_t)(bm + srow) * INSZ + kq;
    const float* wb0 = W1 + (size_t)(bn + srow) * INSZ + kq;

    for (int it = 0; it < 25; ++it) {
        const int k0 = it * BK2;
        {
            const bool valid = (k0 + kq) < INSZ;
            float va[8], vb[8];
            if (valid) {
                #pragma unroll
                for (int p = 0; p < 2; ++p) {
                    float4 xv = ((const float4*)(xa0 + k0))[p];
                    float4 bv = ((const float4*)(wb0 + k0))[p];
                    va[4*p+0] = xv.x; va[4*p+1] = xv.y; va[4*p+2] = xv.z; va[4*p+3] = xv.w;
                    vb[4*p+0] = bv.x; vb[4*p+1] = bv.y; vb[4*p+2] = bv.z; vb[4*p+3] = bv.w;
                }
            } else {
                #pragma unroll
                for (int j = 0; j < 8; ++j) { va[j] = 0.f; vb[j] = 0.f; }
            }
            short8 ahi, alo, bhi, blo;
            #pragma unroll
            for (int j = 0; j < 8; ++j) {
                short h1 = f2bf(va[j]);
                short l1 = f2bf(va[j] - bf2f(h1));
                short h2 = f2bf(vb[j]);
                short l2 = f2bf(vb[j] - bf2f(h2));
                ahi[j] = h1;  alo[j] = l1;
                bhi[j] = h2;  blo[j] = l2;
            }
            const int base = srow * LDK2 + kq;
            *(short8*)&Ah[base] = ahi;
            *(short8*)&Al[base] = alo;
            *(short8*)&Bh[base] = bhi;
            *(short8*)&Bl[base] = blo;
        }
        __syncthreads();

        const int aoff = (wv * 16 + lm) * LDK2 + q * 8;
        short8 ah = *(const short8*)&Ah[aoff];
        short8 al = *(const short8*)&Al[aoff];
        #pragma unroll
        for (int fj = 0; fj < 4; ++fj) {
            const int boff = (fj * 16 + lm) * LDK2 + q * 8;
            short8 bh = *(const short8*)&Bh[boff];
            short8 bl = *(const short8*)&Bl[boff];
            acc[fj] = __builtin_amdgcn_mfma_f32_16x16x32_bf16(ah, bh, acc[fj], 0, 0, 0);
            acc[fj] = __builtin_amdgcn_mfma_f32_16x16x32_bf16(ah, bl, acc[fj], 0, 0, 0);
            acc[fj] = __builtin_amdgcn_mfma_f32_16x16x32_bf16(al, bh, acc[fj], 0, 0, 0);
        }
        __syncthreads();
    }

    #pragma unroll
    for (int fj = 0; fj < 4; ++fj) {
        const int col  = bn + fj * 16 + lm;
        const float bias = b1[col];
        const int row0 = bm + wv * 16 + q * 4;
        #pragma unroll
        for (int r = 0; r < 4; ++r)
            h[(size_t)(row0 + r) * SYS + col] = acc[fj][r] + bias;
    }
}

// ---------------------------------------------------------------------------
// RK4 Lorenz-96 + GEMM2 + log_softmax — unchanged (at the measured VALU
// roofline: 19 slots/elem/step -> ~308 us at m07's 66%-of-peak issue rate;
// we measure 304 us, VALUBusy 79%, MfmaUtil 0, HBM 1%). Do not revisit
// DPP (r5) or 8-wave twist (r9); both regressed.
// ---------------------------------------------------------------------------
__global__ __launch_bounds__(256, 4) void rk4_kernel(
    const float* __restrict__ hbuf, const float* __restrict__ W2,
    const float* __restrict__ b2, float* __restrict__ out)
{
    const int lane = threadIdx.x & 63;
    const int w    = threadIdx.x >> 6;
    const int rowA = blockIdx.x * 8 + w * 2;
    const int rowB = rowA + 1;

    const int laneL = (lane + 63) & 63;
    const int laneR = (lane + 1) & 63;

    v2f X[16];
    {
        const float4* a4 = (const float4*)(hbuf + (size_t)rowA * SYS) + lane * 4;
        const float4* b4 = (const float4*)(hbuf + (size_t)rowB * SYS) + lane * 4;
        #pragma unroll
        for (int k = 0; k < 4; ++k) {
            float4 av = a4[k], bv = b4[k];
            X[4*k+0] = mk2(av.x, bv.x);
            X[4*k+1] = mk2(av.y, bv.y);
            X[4*k+2] = mk2(av.z, bv.z);
            X[4*k+3] = mk2(av.w, bv.w);
        }
    }

    const v2f Fv     = mk2(FFORCE, FFORCE);
    const v2f c_half = mk2(0.5f * HSTEP, 0.5f * HSTEP);
    const v2f c_full = mk2(HSTEP, HSTEP);
    const v2f c_two  = mk2(2.0f, 2.0f);
    const v2f c_six  = mk2(HSTEP / 6.0f, HSTEP / 6.0f);

    v2f acc[16], T[16];

    auto deriv_ip = [&](v2f (&y)[16], v2f r1, v2f l1, v2f l2) {
        v2f y0o = y[0], y1o = y[1], y2o = y[2];
        v2f d0 = Fv - y[0], d1 = Fv - y[1], d15 = Fv - y[15];
        v2f p2 = y0o, p1 = y1o, cur = y[2];
        #pragma unroll
        for (int i = 2; i < 15; ++i) {
            v2f yp1 = (i < 14) ? y[i + 1] : y[15];
            v2f nv  = pkfma(yp1 - p2, p1, Fv - cur);
            p2 = p1; p1 = cur;
            if (i < 14) cur = y[i + 1];
            y[i] = nv;
        }
        y[15] = pkfma(r1 - p2, p1, d15);
        y[1]  = pkfma(y2o - l1, y0o, d1);
        y[0]  = pkfma(y1o - l2, l1, d0);
    };

    v2f r1x = sh2(X[0],  laneR);
    v2f l1x = sh2(X[15], laneL);
    v2f l2x = sh2(X[14], laneL);

    #pragma unroll 1
    for (int s = 0; s < NSTEP; ++s) {
        #pragma unroll
        for (int i = 2; i < 15; ++i)
            acc[i] = pkfma(X[i + 1] - X[i - 2], X[i - 1], Fv - X[i]);
        acc[15] = pkfma(r1x - X[13], X[14], Fv - X[15]);
        acc[1]  = pkfma(X[2] - l1x, X[0],  Fv - X[1]);
        acc[0]  = pkfma(X[1] - l2x, l1x,   Fv - X[0]);

        T[14] = pkfma(c_half, acc[14], X[14]);
        T[15] = pkfma(c_half, acc[15], X[15]);
        T[0]  = pkfma(c_half, acc[0],  X[0]);
        v2f r1 = sh2(T[0],  laneR);
        v2f l1 = sh2(T[15], laneL);
        v2f l2 = sh2(T[14], laneL);
        #pragma unroll
        for (int i = 1; i < 14; ++i) T[i] = pkfma(c_half, acc[i], X[i]);
        deriv_ip(T, r1, l1, l2);

        {
            v2f a;
            a = T[14]; acc[14] = pkfma(c_two, a, acc[14]); T[14] = pkfma(c_half, a, X[14]);
            a = T[15]; acc[15] = pkfma(c_two, a, acc[15]); T[15] = pkfma(c_half, a, X[15]);
            a = T[0];  acc[0]  = pkfma(c_two, a, acc[0]);  T[0]  = pkfma(c_half, a, X[0]);
            r1 = sh2(T[0],  laneR);
            l1 = sh2(T[15], laneL);
            l2 = sh2(T[14], laneL);
            #pragma unroll
            for (int i = 1; i < 14; ++i) {
                a = T[i]; acc[i] = pkfma(c_two, a, acc[i]); T[i] = pkfma(c_half, a, X[i]);
            }
        }
        deriv_ip(T, r1, l1, l2);

        {
            v2f a;
            a = T[14]; acc[14] = pkfma(c_two, a, acc[14]); T[14] = pkfma(c_full, a, X[14]);
            a = T[15]; acc[15] = pkfma(c_two, a, acc[15]); T[15] = pkfma(c_full, a, X[15]);
            a = T[0];  acc[0]  = pkfma(c_two, a, acc[0]);  T[0]  = pkfma(c_full, a, X[0]);
            r1 = sh2(T[0],  laneR);
            l1 = sh2(T[15], laneL);
            l2 = sh2(T[14], laneL);
            #pragma unroll
            for (int i = 1; i < 14; ++i) {
                a = T[i]; acc[i] = pkfma(c_two, a, acc[i]); T[i] = pkfma(c_full, a, X[i]);
            }
        }
        deriv_ip(T, r1, l1, l2);

        X[14] = pkfma(c_six, acc[14] + T[14], X[14]);
        X[15] = pkfma(c_six, acc[15] + T[15], X[15]);
        X[0]  = pkfma(c_six, acc[0]  + T[0],  X[0]);
        r1x = sh2(X[0],  laneR);
        l1x = sh2(X[15], laneL);
        l2x = sh2(X[14], laneL);
        #pragma unroll
        for (int i = 1; i < 14; ++i)
            X[i] = pkfma(c_six, acc[i] + T[i], X[i]);
    }

    v2f l[OUTSZ];
    #pragma unroll
    for (int o = 0; o < OUTSZ; ++o) {
        const float4* w4 = (const float4*)(W2 + (size_t)o * SYS) + lane * 4;
        v2f s2 = mk2(0.f, 0.f);
        #pragma unroll
        for (int k = 0; k < 4; ++k) {
            float4 wv = w4[k];
            s2 = pkfma(X[4*k+0], mk2(wv.x, wv.x), s2);
            s2 = pkfma(X[4*k+1], mk2(wv.y, wv.y), s2);
            s2 = pkfma(X[4*k+2], mk2(wv.z, wv.z), s2);
            s2 = pkfma(X[4*k+3], mk2(wv.w, wv.w), s2);
        }
        #pragma unroll
        for (int dlt = 1; dlt < 64; dlt <<= 1) {
            s2.x += __shfl_xor(s2.x, dlt);
            s2.y += __shfl_xor(s2.y, dlt);
        }
        const float bo = b2[o];
        l[o] = s2 + mk2(bo, bo);
    }

    v2f m = l[0];
    #pragma unroll
    for (int o = 1; o < OUTSZ; ++o) m = __builtin_elementwise_max(m, l[o]);
    v2f ssum = mk2(0.f, 0.f);
    #pragma unroll
    for (int o = 0; o < OUTSZ; ++o) {
        v2f d = l[o] - m;
        ssum = ssum + mk2(__expf(d.x), __expf(d.y));
    }
    const v2f lse = m + mk2(__logf(ssum.x), __logf(ssum.y));

    float vA = l[0].x - lse.x;
    float vB = l[0].y - lse.y;
    #pragma unroll
    for (int o = 1; o < OUTSZ; ++o) {
        if (lane == o) { vA = l[o].x - lse.x; vB = l[o].y - lse.y; }
    }
    if (lane < OUTSZ) {
        out[(size_t)rowA * OUTSZ + lane] = vA;
        out[(size_t)rowB * OUTSZ + lane] = vB;
    }
}

extern "C" void kernel_launch(void* const* d_in, const int* in_sizes, int n_in,
                              void* d_out, int out_size, void* d_ws, size_t ws_size,
                              hipStream_t stream)
{
    const float* x  = (const float*)d_in[0];
    const float* W1 = (const float*)d_in[1];
    const float* b1 = (const float*)d_in[2];
    const float* W2 = (const float*)d_in[3];
    const float* b2 = (const float*)d_in[4];
    float* out = (float*)d_out;
    float* h   = (float*)d_ws;   // 8192*1024*4 = 33.5 MB scratch

    const size_t hbytes    = (size_t)BATCH * SYS * sizeof(float);
    const size_t splitshorts = (size_t)(BATCH + SYS) * KP;           // per hi/lo pair member
    const size_t need      = hbytes + 2 * splitshorts * sizeof(short);

    dim3 g1(SYS / BN2, BATCH / BM2);   // 16 x 128 = 2048 blocks

    if (ws_size >= need) {
        short* xh = (short*)((char*)d_ws + hbytes);
        short* xl = xh + (size_t)BATCH * KP;
        short* wh = xl + (size_t)BATCH * KP;
        short* wl = wh + (size_t)SYS * KP;
        convert_kernel<<<2048, 256, 0, stream>>>(x, W1, xh, xl, wh, wl);
        gemm1s_kernel<<<g1, 256, 0, stream>>>(xh, xl, wh, wl, b1, h);
    } else {
        gemm1_kernel<<<g1, 256, 0, stream>>>(x, W1, b1, h);   // fallback
    }

    rk4_kernel<<<BATCH / 8, 256, 0, stream>>>(h, W2, b2, out);  // 1024 blocks, 2 rows/wave
}

// Round 2
// 425.657 us; speedup vs baseline: 1.0103x; 1.0103x over previous
//
#include <hip/hip_runtime.h>
#include <hip/hip_bf16.h>
#include <math.h>

#define BATCH 8192
#define INSZ 784
#define SYS 1024
#define OUTSZ 10
#define NSTEP 100
#define HSTEP 0.01f
#define FFORCE 8.0f
#define KP 800   // 25*32: K padded for pre-split arrays (784..799 zero-filled)

typedef short short8 __attribute__((ext_vector_type(8)));
typedef float float4v __attribute__((ext_vector_type(4)));
typedef float v2f __attribute__((ext_vector_type(2)));

static __device__ __forceinline__ short f2bf(float x) {
    __hip_bfloat16 b = __float2bfloat16(x);   // RNE
    return __builtin_bit_cast(short, b);
}
static __device__ __forceinline__ float bf2f(short s) {
    unsigned int u = ((unsigned int)(unsigned short)s) << 16;
    return __builtin_bit_cast(float, u);
}

static __device__ __forceinline__ v2f pkfma(v2f a, v2f b, v2f c) {
    return __builtin_elementwise_fma(a, b, c);
}
static __device__ __forceinline__ v2f mk2(float x, float y) {
    v2f r; r.x = x; r.y = y; return r;
}
static __device__ __forceinline__ v2f sh2(v2f v, int ln) {
    v2f r; r.x = __shfl(v.x, ln); r.y = __shfl(v.y, ln); return r;
}

// ---------------------------------------------------------------------------
// convert_kernel: one-shot fp32 -> split-bf16 (hi + lo residual, RNE).
// Unchanged from r1 (verified bit-identical: absmax 0.03125 both rounds).
// ---------------------------------------------------------------------------
__global__ __launch_bounds__(256) void convert_kernel(
    const float* __restrict__ x, const float* __restrict__ W1,
    short* __restrict__ xh, short* __restrict__ xl,
    short* __restrict__ wh, short* __restrict__ wl)
{
    const int total = (BATCH + SYS) * (KP / 8);   // 921600 8-elem chunks
    for (int idx = blockIdx.x * blockDim.x + threadIdx.x; idx < total;
         idx += gridDim.x * blockDim.x) {
        const int row = idx / (KP / 8);
        const int ck  = idx - row * (KP / 8);

        short8 hi, lo;
        if (ck < INSZ / 8) {
            const float* src = (row < BATCH)
                ? (x + (size_t)row * INSZ)
                : (W1 + (size_t)(row - BATCH) * INSZ);
            float4 v0 = ((const float4*)src)[ck * 2];
            float4 v1 = ((const float4*)src)[ck * 2 + 1];
            float vv[8] = {v0.x, v0.y, v0.z, v0.w, v1.x, v1.y, v1.z, v1.w};
            #pragma unroll
            for (int j = 0; j < 8; ++j) {
                short hj = f2bf(vv[j]);
                hi[j] = hj;
                lo[j] = f2bf(vv[j] - bf2f(hj));
            }
        } else {
            #pragma unroll
            for (int j = 0; j < 8; ++j) { hi[j] = 0; lo[j] = 0; }
        }

        short* dh; short* dl;
        if (row < BATCH) {
            dh = xh + (size_t)row * KP;
            dl = xl + (size_t)row * KP;
        } else {
            dh = wh + (size_t)(row - BATCH) * KP;
            dl = wl + (size_t)(row - BATCH) * KP;
        }
        *(short8*)(dh + ck * 8) = hi;
        *(short8*)(dl + ck * 8) = lo;
    }
}

// ---------------------------------------------------------------------------
// GEMM1 (pre-split, 128x128 tile): h = x @ W1^T + b1.
// r1 post-mortem: removing conversion VALU at 64x64 changed nothing ->
// phase is LDS-traffic + global-re-read + latency bound. 128x128/8-wave:
//   LDS traffic 2.46 GB -> 1.64 GB (12 ds_read per 24 MFMA per wave-iter)
//   global reads 840 MB -> 420 MB (x re-read 8x not 16x, W1 64x not 128x)
//   2 independent blocks/CU (16 waves/CU) so barrier drains cross-cover.
// ---------------------------------------------------------------------------
#define BM3 128
#define BN3 128
#define BK3 32
#define LDK3 40   // shorts; 80 B row stride -> 2-way bank alias only (free)

__global__ __launch_bounds__(512, 2) void gemm1s_kernel(
    const short* __restrict__ xh, const short* __restrict__ xl,
    const short* __restrict__ wh, const short* __restrict__ wl,
    const float* __restrict__ b1, float* __restrict__ h)
{
    __shared__ short Ah[BM3 * LDK3], Al[BM3 * LDK3];
    __shared__ short Bh[BN3 * LDK3], Bl[BN3 * LDK3];   // 4 * 10240 B = 41 KB

    const int t  = threadIdx.x;           // 0..511
    const int bm = blockIdx.y * BM3;
    const int bn = blockIdx.x * BN3;

    // staging role: 4 lanes per row, 8 contiguous shorts per lane, 128 rows
    const int srow = t >> 2;              // 0..127
    const int kq   = (t & 3) * 8;         // 0,8,16,24

    // compute role: 8 waves; wave owns a 32x64 output sub-tile
    const int wv   = t >> 6;              // 0..7
    const int wr   = wv >> 1;             // 0..3: row quarter (32 rows)
    const int wc   = wv & 1;              // 0..1: col half (64 cols)
    const int lane = t & 63;
    const int lm   = lane & 15;
    const int q    = lane >> 4;

    float4v acc[2][4];
    #pragma unroll
    for (int mi = 0; mi < 2; ++mi)
        #pragma unroll
        for (int nj = 0; nj < 4; ++nj) {
            acc[mi][nj][0] = 0.f; acc[mi][nj][1] = 0.f;
            acc[mi][nj][2] = 0.f; acc[mi][nj][3] = 0.f;
        }

    const short* pxh = xh + (size_t)(bm + srow) * KP + kq;
    const short* pxl = xl + (size_t)(bm + srow) * KP + kq;
    const short* pwh = wh + (size_t)(bn + srow) * KP + kq;
    const short* pwl = wl + (size_t)(bn + srow) * KP + kq;
    const int sbase = srow * LDK3 + kq;

    // prologue: K-slab 0 into registers
    short8 ra = *(const short8*)(pxh);
    short8 rb = *(const short8*)(pxl);
    short8 rc = *(const short8*)(pwh);
    short8 rd = *(const short8*)(pwl);

    for (int it = 0; it < 25; ++it) {
        *(short8*)&Ah[sbase] = ra;
        *(short8*)&Al[sbase] = rb;
        *(short8*)&Bh[sbase] = rc;
        *(short8*)&Bl[sbase] = rd;
        __syncthreads();

        if (it < 24) {   // issue next slab's loads; hide under 24 MFMA
            const int k1 = (it + 1) * BK3;
            ra = *(const short8*)(pxh + k1);
            rb = *(const short8*)(pxl + k1);
            rc = *(const short8*)(pwh + k1);
            rd = *(const short8*)(pwl + k1);
        }

        short8 fah[2], fal[2];
        #pragma unroll
        for (int mi = 0; mi < 2; ++mi) {
            const int ao = (wr * 32 + mi * 16 + lm) * LDK3 + q * 8;
            fah[mi] = *(const short8*)&Ah[ao];
            fal[mi] = *(const short8*)&Al[ao];
        }
        #pragma unroll
        for (int nj = 0; nj < 4; ++nj) {
            const int bo = (wc * 64 + nj * 16 + lm) * LDK3 + q * 8;
            short8 bh = *(const short8*)&Bh[bo];
            short8 bl = *(const short8*)&Bl[bo];
            #pragma unroll
            for (int mi = 0; mi < 2; ++mi) {
                acc[mi][nj] = __builtin_amdgcn_mfma_f32_16x16x32_bf16(fah[mi], bh, acc[mi][nj], 0, 0, 0);
                acc[mi][nj] = __builtin_amdgcn_mfma_f32_16x16x32_bf16(fah[mi], bl, acc[mi][nj], 0, 0, 0);
                acc[mi][nj] = __builtin_amdgcn_mfma_f32_16x16x32_bf16(fal[mi], bh, acc[mi][nj], 0, 0, 0);
            }
        }
        __syncthreads();
    }

    // epilogue: + b1, store fp32. C/D: col = lm, row = q*4 + r.
    #pragma unroll
    for (int mi = 0; mi < 2; ++mi) {
        const int row0 = bm + wr * 32 + mi * 16 + q * 4;
        #pragma unroll
        for (int nj = 0; nj < 4; ++nj) {
            const int col  = bn + wc * 64 + nj * 16 + lm;
            const float bias = b1[col];
            #pragma unroll
            for (int r = 0; r < 4; ++r)
                h[(size_t)(row0 + r) * SYS + col] = acc[mi][nj][r] + bias;
        }
    }
}

// ---------------------------------------------------------------------------
// GEMM1 fallback (in-kernel conversion, 64x64) — only if workspace too small.
// ---------------------------------------------------------------------------
#define BM2 64
#define BN2 64
#define BK2 32
#define LDK2 40

__global__ __launch_bounds__(256, 4) void gemm1_kernel(
    const float* __restrict__ x, const float* __restrict__ W1,
    const float* __restrict__ b1, float* __restrict__ h)
{
    __shared__ short Ah[BM2 * LDK2], Al[BM2 * LDK2];
    __shared__ short Bh[BN2 * LDK2], Bl[BN2 * LDK2];

    const int t  = threadIdx.x;
    const int bm = blockIdx.y * BM2;
    const int bn = blockIdx.x * BN2;

    const int srow = t >> 2;
    const int kq   = (t & 3) * 8;

    const int wv   = t >> 6;
    const int lane = t & 63;
    const int lm   = lane & 15;
    const int q    = lane >> 4;

    float4v acc[4];
    #pragma unroll
    for (int j = 0; j < 4; ++j) {
        acc[j][0] = 0.f; acc[j][1] = 0.f; acc[j][2] = 0.f; acc[j][3] = 0.f;
    }

    const float* xa0 = x  + (size_t)(bm + srow) * INSZ + kq;
    const float* wb0 = W1 + (size_t)(bn + srow) * INSZ + kq;

    for (int it = 0; it < 25; ++it) {
        const int k0 = it * BK2;
        {
            const bool valid = (k0 + kq) < INSZ;
            float va[8], vb[8];
            if (valid) {
                #pragma unroll
                for (int p = 0; p < 2; ++p) {
                    float4 xv = ((const float4*)(xa0 + k0))[p];
                    float4 bv = ((const float4*)(wb0 + k0))[p];
                    va[4*p+0] = xv.x; va[4*p+1] = xv.y; va[4*p+2] = xv.z; va[4*p+3] = xv.w;
                    vb[4*p+0] = bv.x; vb[4*p+1] = bv.y; vb[4*p+2] = bv.z; vb[4*p+3] = bv.w;
                }
            } else {
                #pragma unroll
                for (int j = 0; j < 8; ++j) { va[j] = 0.f; vb[j] = 0.f; }
            }
            short8 ahi, alo, bhi, blo;
            #pragma unroll
            for (int j = 0; j < 8; ++j) {
                short h1 = f2bf(va[j]);
                short l1 = f2bf(va[j] - bf2f(h1));
                short h2 = f2bf(vb[j]);
                short l2 = f2bf(vb[j] - bf2f(h2));
                ahi[j] = h1;  alo[j] = l1;
                bhi[j] = h2;  blo[j] = l2;
            }
            const int base = srow * LDK2 + kq;
            *(short8*)&Ah[base] = ahi;
            *(short8*)&Al[base] = alo;
            *(short8*)&Bh[base] = bhi;
            *(short8*)&Bl[base] = blo;
        }
        __syncthreads();

        const int aoff = (wv * 16 + lm) * LDK2 + q * 8;
        short8 ah = *(const short8*)&Ah[aoff];
        short8 al = *(const short8*)&Al[aoff];
        #pragma unroll
        for (int fj = 0; fj < 4; ++fj) {
            const int boff = (fj * 16 + lm) * LDK2 + q * 8;
            short8 bh = *(const short8*)&Bh[boff];
            short8 bl = *(const short8*)&Bl[boff];
            acc[fj] = __builtin_amdgcn_mfma_f32_16x16x32_bf16(ah, bh, acc[fj], 0, 0, 0);
            acc[fj] = __builtin_amdgcn_mfma_f32_16x16x32_bf16(ah, bl, acc[fj], 0, 0, 0);
            acc[fj] = __builtin_amdgcn_mfma_f32_16x16x32_bf16(al, bh, acc[fj], 0, 0, 0);
        }
        __syncthreads();
    }

    #pragma unroll
    for (int fj = 0; fj < 4; ++fj) {
        const int col  = bn + fj * 16 + lm;
        const float bias = b1[col];
        const int row0 = bm + wv * 16 + q * 4;
        #pragma unroll
        for (int r = 0; r < 4; ++r)
            h[(size_t)(row0 + r) * SYS + col] = acc[fj][r] + bias;
    }
}

// ---------------------------------------------------------------------------
// RK4 Lorenz-96 + GEMM2 + log_softmax — unchanged (measured VALU roofline:
// 19 slots/elem/step -> ~300 us; VALUBusy ~80%, MfmaUtil 0, HBM ~1%).
// ---------------------------------------------------------------------------
__global__ __launch_bounds__(256, 4) void rk4_kernel(
    const float* __restrict__ hbuf, const float* __restrict__ W2,
    const float* __restrict__ b2, float* __restrict__ out)
{
    const int lane = threadIdx.x & 63;
    const int w    = threadIdx.x >> 6;
    const int rowA = blockIdx.x * 8 + w * 2;
    const int rowB = rowA + 1;

    const int laneL = (lane + 63) & 63;
    const int laneR = (lane + 1) & 63;

    v2f X[16];
    {
        const float4* a4 = (const float4*)(hbuf + (size_t)rowA * SYS) + lane * 4;
        const float4* b4 = (const float4*)(hbuf + (size_t)rowB * SYS) + lane * 4;
        #pragma unroll
        for (int k = 0; k < 4; ++k) {
            float4 av = a4[k], bv = b4[k];
            X[4*k+0] = mk2(av.x, bv.x);
            X[4*k+1] = mk2(av.y, bv.y);
            X[4*k+2] = mk2(av.z, bv.z);
            X[4*k+3] = mk2(av.w, bv.w);
        }
    }

    const v2f Fv     = mk2(FFORCE, FFORCE);
    const v2f c_half = mk2(0.5f * HSTEP, 0.5f * HSTEP);
    const v2f c_full = mk2(HSTEP, HSTEP);
    const v2f c_two  = mk2(2.0f, 2.0f);
    const v2f c_six  = mk2(HSTEP / 6.0f, HSTEP / 6.0f);

    v2f acc[16], T[16];

    auto deriv_ip = [&](v2f (&y)[16], v2f r1, v2f l1, v2f l2) {
        v2f y0o = y[0], y1o = y[1], y2o = y[2];
        v2f d0 = Fv - y[0], d1 = Fv - y[1], d15 = Fv - y[15];
        v2f p2 = y0o, p1 = y1o, cur = y[2];
        #pragma unroll
        for (int i = 2; i < 15; ++i) {
            v2f yp1 = (i < 14) ? y[i + 1] : y[15];
            v2f nv  = pkfma(yp1 - p2, p1, Fv - cur);
            p2 = p1; p1 = cur;
            if (i < 14) cur = y[i + 1];
            y[i] = nv;
        }
        y[15] = pkfma(r1 - p2, p1, d15);
        y[1]  = pkfma(y2o - l1, y0o, d1);
        y[0]  = pkfma(y1o - l2, l1, d0);
    };

    v2f r1x = sh2(X[0],  laneR);
    v2f l1x = sh2(X[15], laneL);
    v2f l2x = sh2(X[14], laneL);

    #pragma unroll 1
    for (int s = 0; s < NSTEP; ++s) {
        #pragma unroll
        for (int i = 2; i < 15; ++i)
            acc[i] = pkfma(X[i + 1] - X[i - 2], X[i - 1], Fv - X[i]);
        acc[15] = pkfma(r1x - X[13], X[14], Fv - X[15]);
        acc[1]  = pkfma(X[2] - l1x, X[0],  Fv - X[1]);
        acc[0]  = pkfma(X[1] - l2x, l1x,   Fv - X[0]);

        T[14] = pkfma(c_half, acc[14], X[14]);
        T[15] = pkfma(c_half, acc[15], X[15]);
        T[0]  = pkfma(c_half, acc[0],  X[0]);
        v2f r1 = sh2(T[0],  laneR);
        v2f l1 = sh2(T[15], laneL);
        v2f l2 = sh2(T[14], laneL);
        #pragma unroll
        for (int i = 1; i < 14; ++i) T[i] = pkfma(c_half, acc[i], X[i]);
        deriv_ip(T, r1, l1, l2);

        {
            v2f a;
            a = T[14]; acc[14] = pkfma(c_two, a, acc[14]); T[14] = pkfma(c_half, a, X[14]);
            a = T[15]; acc[15] = pkfma(c_two, a, acc[15]); T[15] = pkfma(c_half, a, X[15]);
            a = T[0];  acc[0]  = pkfma(c_two, a, acc[0]);  T[0]  = pkfma(c_half, a, X[0]);
            r1 = sh2(T[0],  laneR);
            l1 = sh2(T[15], laneL);
            l2 = sh2(T[14], laneL);
            #pragma unroll
            for (int i = 1; i < 14; ++i) {
                a = T[i]; acc[i] = pkfma(c_two, a, acc[i]); T[i] = pkfma(c_half, a, X[i]);
            }
        }
        deriv_ip(T, r1, l1, l2);

        {
            v2f a;
            a = T[14]; acc[14] = pkfma(c_two, a, acc[14]); T[14] = pkfma(c_full, a, X[14]);
            a = T[15]; acc[15] = pkfma(c_two, a, acc[15]); T[15] = pkfma(c_full, a, X[15]);
            a = T[0];  acc[0]  = pkfma(c_two, a, acc[0]);  T[0]  = pkfma(c_full, a, X[0]);
            r1 = sh2(T[0],  laneR);
            l1 = sh2(T[15], laneL);
            l2 = sh2(T[14], laneL);
            #pragma unroll
            for (int i = 1; i < 14; ++i) {
                a = T[i]; acc[i] = pkfma(c_two, a, acc[i]); T[i] = pkfma(c_full, a, X[i]);
            }
        }
        deriv_ip(T, r1, l1, l2);

        X[14] = pkfma(c_six, acc[14] + T[14], X[14]);
        X[15] = pkfma(c_six, acc[15] + T[15], X[15]);
        X[0]  = pkfma(c_six, acc[0]  + T[0],  X[0]);
        r1x = sh2(X[0],  laneR);
        l1x = sh2(X[15], laneL);
        l2x = sh2(X[14], laneL);
        #pragma unroll
        for (int i = 1; i < 14; ++i)
            X[i] = pkfma(c_six, acc[i] + T[i], X[i]);
    }

    v2f l[OUTSZ];
    #pragma unroll
    for (int o = 0; o < OUTSZ; ++o) {
        const float4* w4 = (const float4*)(W2 + (size_t)o * SYS) + lane * 4;
        v2f s2 = mk2(0.f, 0.f);
        #pragma unroll
        for (int k = 0; k < 4; ++k) {
            float4 wv = w4[k];
            s2 = pkfma(X[4*k+0], mk2(wv.x, wv.x), s2);
            s2 = pkfma(X[4*k+1], mk2(wv.y, wv.y), s2);
            s2 = pkfma(X[4*k+2], mk2(wv.z, wv.z), s2);
            s2 = pkfma(X[4*k+3], mk2(wv.w, wv.w), s2);
        }
        #pragma unroll
        for (int dlt = 1; dlt < 64; dlt <<= 1) {
            s2.x += __shfl_xor(s2.x, dlt);
            s2.y += __shfl_xor(s2.y, dlt);
        }
        const float bo = b2[o];
        l[o] = s2 + mk2(bo, bo);
    }

    v2f m = l[0];
    #pragma unroll
    for (int o = 1; o < OUTSZ; ++o) m = __builtin_elementwise_max(m, l[o]);
    v2f ssum = mk2(0.f, 0.f);
    #pragma unroll
    for (int o = 0; o < OUTSZ; ++o) {
        v2f d = l[o] - m;
        ssum = ssum + mk2(__expf(d.x), __expf(d.y));
    }
    const v2f lse = m + mk2(__logf(ssum.x), __logf(ssum.y));

    float vA = l[0].x - lse.x;
    float vB = l[0].y - lse.y;
    #pragma unroll
    for (int o = 1; o < OUTSZ; ++o) {
        if (lane == o) { vA = l[o].x - lse.x; vB = l[o].y - lse.y; }
    }
    if (lane < OUTSZ) {
        out[(size_t)rowA * OUTSZ + lane] = vA;
        out[(size_t)rowB * OUTSZ + lane] = vB;
    }
}

extern "C" void kernel_launch(void* const* d_in, const int* in_sizes, int n_in,
                              void* d_out, int out_size, void* d_ws, size_t ws_size,
                              hipStream_t stream)
{
    const float* x  = (const float*)d_in[0];
    const float* W1 = (const float*)d_in[1];
    const float* b1 = (const float*)d_in[2];
    const float* W2 = (const float*)d_in[3];
    const float* b2 = (const float*)d_in[4];
    float* out = (float*)d_out;
    float* h   = (float*)d_ws;   // 8192*1024*4 = 33.5 MB scratch

    const size_t hbytes      = (size_t)BATCH * SYS * sizeof(float);
    const size_t splitshorts = (size_t)(BATCH + SYS) * KP;           // per hi/lo member
    const size_t need        = hbytes + 2 * splitshorts * sizeof(short);

    if (ws_size >= need) {
        short* xh = (short*)((char*)d_ws + hbytes);
        short* xl = xh + (size_t)BATCH * KP;
        short* wh = xl + (size_t)BATCH * KP;
        short* wl = wh + (size_t)SYS * KP;
        convert_kernel<<<2048, 256, 0, stream>>>(x, W1, xh, xl, wh, wl);
        dim3 g1(SYS / BN3, BATCH / BM3);   // 8 x 64 = 512 blocks, 512 threads
        gemm1s_kernel<<<g1, 512, 0, stream>>>(xh, xl, wh, wl, b1, h);
    } else {
        dim3 g1(SYS / BN2, BATCH / BM2);   // fallback: 16 x 128 = 2048 blocks
        gemm1_kernel<<<g1, 256, 0, stream>>>(x, W1, b1, h);
    }

    rk4_kernel<<<BATCH / 8, 256, 0, stream>>>(h, W2, b2, out);  // 1024 blocks
}

// Round 3
// 419.502 us; speedup vs baseline: 1.0251x; 1.0147x over previous
//
#include <hip/hip_runtime.h>
#include <hip/hip_bf16.h>
#include <math.h>

#define BATCH 8192
#define INSZ 784
#define SYS 1024
#define OUTSZ 10
#define NSTEP 100
#define HSTEP 0.01f
#define FFORCE 8.0f
#define KP 800   // 25*32: K padded for pre-split arrays (784..799 zero-filled)

typedef short short8 __attribute__((ext_vector_type(8)));
typedef float float4v __attribute__((ext_vector_type(4)));
typedef float v2f __attribute__((ext_vector_type(2)));

static __device__ __forceinline__ short f2bf(float x) {
    __hip_bfloat16 b = __float2bfloat16(x);   // RNE
    return __builtin_bit_cast(short, b);
}
static __device__ __forceinline__ float bf2f(short s) {
    unsigned int u = ((unsigned int)(unsigned short)s) << 16;
    return __builtin_bit_cast(float, u);
}

static __device__ __forceinline__ v2f pkfma(v2f a, v2f b, v2f c) {
    return __builtin_elementwise_fma(a, b, c);
}
static __device__ __forceinline__ v2f mk2(float x, float y) {
    v2f r; r.x = x; r.y = y; return r;
}
static __device__ __forceinline__ v2f sh2(v2f v, int ln) {
    v2f r; r.x = __shfl(v.x, ln); r.y = __shfl(v.y, ln); return r;
}

// 16B global -> LDS DMA (vmcnt-tracked; drains at __syncthreads)
static __device__ __forceinline__ void gld_lds16(const void* g, void* l) {
    __builtin_amdgcn_global_load_lds(
        (const __attribute__((address_space(1))) unsigned int*)g,
        (__attribute__((address_space(3))) unsigned int*)l, 16, 0, 0);
}

// ---------------------------------------------------------------------------
// convert_kernel: one-shot fp32 -> split-bf16 (hi + lo residual, RNE).
// Bit-identical to the in-gemm conversion (absmax 0.03125 all rounds).
// ---------------------------------------------------------------------------
__global__ __launch_bounds__(256) void convert_kernel(
    const float* __restrict__ x, const float* __restrict__ W1,
    short* __restrict__ xh, short* __restrict__ xl,
    short* __restrict__ wh, short* __restrict__ wl)
{
    const int total = (BATCH + SYS) * (KP / 8);   // 921600 8-elem chunks
    for (int idx = blockIdx.x * blockDim.x + threadIdx.x; idx < total;
         idx += gridDim.x * blockDim.x) {
        const int row = idx / (KP / 8);
        const int ck  = idx - row * (KP / 8);

        short8 hi, lo;
        if (ck < INSZ / 8) {
            const float* src = (row < BATCH)
                ? (x + (size_t)row * INSZ)
                : (W1 + (size_t)(row - BATCH) * INSZ);
            float4 v0 = ((const float4*)src)[ck * 2];
            float4 v1 = ((const float4*)src)[ck * 2 + 1];
            float vv[8] = {v0.x, v0.y, v0.z, v0.w, v1.x, v1.y, v1.z, v1.w};
            #pragma unroll
            for (int j = 0; j < 8; ++j) {
                short hj = f2bf(vv[j]);
                hi[j] = hj;
                lo[j] = f2bf(vv[j] - bf2f(hj));
            }
        } else {
            #pragma unroll
            for (int j = 0; j < 8; ++j) { hi[j] = 0; lo[j] = 0; }
        }

        short* dh; short* dl;
        if (row < BATCH) {
            dh = xh + (size_t)row * KP;
            dl = xl + (size_t)row * KP;
        } else {
            dh = wh + (size_t)(row - BATCH) * KP;
            dl = wl + (size_t)(row - BATCH) * KP;
        }
        *(short8*)(dh + ck * 8) = hi;
        *(short8*)(dl + ck * 8) = lo;
    }
}

// ---------------------------------------------------------------------------
// GEMM1 v3: h = x @ W1^T + b1, 128x128 / BK=32, global_load_lds staging.
// r2 post-mortem: traffic cuts (-33% LDS, -50% global) moved nothing ->
// phase is staging-structure bound (reg-stage vmcnt(0)+ds_write serialization,
// m151: 646 vs 874 TF). This version:
//  - global_load_lds width 16 DMA (no VGPR roundtrip, no ds_write; the
//    ladder's biggest rung, m97)
//  - LDK=32 unpadded: DMA dest linear in lane (w*1024 + lane*16 B), and
//    frag ds_read_b128 hits 256 distinct words = 8/bank = conflict-free floor
//  - m97 2-barrier loop: loads for slab it+1 issued before MFMA of slab it
//  - XCD-chunked swizzle (512 blocks % 8 == 0, bijective) for L2 panel reuse
// ---------------------------------------------------------------------------
#define BM3 128
#define BN3 128
#define BK3 32

__global__ __launch_bounds__(512, 4) void gemm1s_kernel(
    const short* __restrict__ xh, const short* __restrict__ xl,
    const short* __restrict__ wh, const short* __restrict__ wl,
    const float* __restrict__ b1, float* __restrict__ h)
{
    __shared__ short Ah[BM3 * BK3], Al[BM3 * BK3];
    __shared__ short Bh[BN3 * BK3], Bl[BN3 * BK3];   // 4 * 8 KB = 32 KB

    const int t = threadIdx.x;            // 0..511

    // XCD-chunked bijective swizzle over the 512-block grid (8 x 64)
    const int lin = blockIdx.y * gridDim.x + blockIdx.x;   // 0..511
    const int nwg = gridDim.x * gridDim.y;                 // 512
    const int cpx = nwg >> 3;                              // 64
    const int swz = (lin & 7) * cpx + (lin >> 3);
    const int bm  = (swz >> 3) * BM3;     // swz / 8 : row panel
    const int bn  = (swz & 7) * BN3;      // swz % 8 : col panel

    // staging role: 4 lanes per row, 16B per lane; wave w covers rows w*16..w*16+15
    const int srow = t >> 2;              // 0..127
    const int wv   = t >> 6;              // 0..7
    const int lane = t & 63;

    // compute role: wave owns a 32x64 output sub-tile
    const int wr   = wv >> 1;             // 0..3
    const int wc   = wv & 1;              // 0..1
    const int lm   = lane & 15;
    const int q    = lane >> 4;

    float4v acc[2][4];
    #pragma unroll
    for (int mi = 0; mi < 2; ++mi)
        #pragma unroll
        for (int nj = 0; nj < 4; ++nj) {
            acc[mi][nj][0] = 0.f; acc[mi][nj][1] = 0.f;
            acc[mi][nj][2] = 0.f; acc[mi][nj][3] = 0.f;
        }

    // per-thread global sources (shorts); 16B-aligned: row*1600 + seg*16
    const short* gxh = xh + (size_t)(bm + srow) * KP + (t & 3) * 8;
    const short* gxl = xl + (size_t)(bm + srow) * KP + (t & 3) * 8;
    const short* gwh = wh + (size_t)(bn + srow) * KP + (t & 3) * 8;
    const short* gwl = wl + (size_t)(bn + srow) * KP + (t & 3) * 8;

    // wave-uniform LDS DMA bases (lane*16B added by HW)
    short* lAh = &Ah[wv * 512];
    short* lAl = &Al[wv * 512];
    short* lBh = &Bh[wv * 512];
    short* lBl = &Bl[wv * 512];

    // prologue: slab 0 in flight
    gld_lds16(gxh, lAh);
    gld_lds16(gxl, lAl);
    gld_lds16(gwh, lBh);
    gld_lds16(gwl, lBl);

    for (int it = 0; it < 25; ++it) {
        __syncthreads();   // vmcnt(0) drain: slab `it` landed for ALL waves

        // LDS -> fragment registers (conflict-free b128)
        short8 fah[2], fal[2], fbh[4], fbl[4];
        #pragma unroll
        for (int mi = 0; mi < 2; ++mi) {
            const int ao = (wr * 32 + mi * 16 + lm) * BK3 + q * 8;
            fah[mi] = *(const short8*)&Ah[ao];
            fal[mi] = *(const short8*)&Al[ao];
        }
        #pragma unroll
        for (int nj = 0; nj < 4; ++nj) {
            const int bo = (wc * 64 + nj * 16 + lm) * BK3 + q * 8;
            fbh[nj] = *(const short8*)&Bh[bo];
            fbl[nj] = *(const short8*)&Bl[bo];
        }
        __syncthreads();   // all frag reads done; safe to overwrite

        if (it < 24) {     // DMA slab it+1; flies under the MFMAs below
            const int k1 = (it + 1) * BK3;
            gld_lds16(gxh + k1, lAh);
            gld_lds16(gxl + k1, lAl);
            gld_lds16(gwh + k1, lBh);
            gld_lds16(gwl + k1, lBl);
        }

        #pragma unroll
        for (int nj = 0; nj < 4; ++nj) {
            #pragma unroll
            for (int mi = 0; mi < 2; ++mi) {
                acc[mi][nj] = __builtin_amdgcn_mfma_f32_16x16x32_bf16(fah[mi], fbh[nj], acc[mi][nj], 0, 0, 0);
                acc[mi][nj] = __builtin_amdgcn_mfma_f32_16x16x32_bf16(fah[mi], fbl[nj], acc[mi][nj], 0, 0, 0);
                acc[mi][nj] = __builtin_amdgcn_mfma_f32_16x16x32_bf16(fal[mi], fbh[nj], acc[mi][nj], 0, 0, 0);
            }
        }
    }

    // epilogue: + b1, store fp32. C/D: col = lm, row = q*4 + r.
    #pragma unroll
    for (int mi = 0; mi < 2; ++mi) {
        const int row0 = bm + wr * 32 + mi * 16 + q * 4;
        #pragma unroll
        for (int nj = 0; nj < 4; ++nj) {
            const int col  = bn + wc * 64 + nj * 16 + lm;
            const float bias = b1[col];
            #pragma unroll
            for (int r = 0; r < 4; ++r)
                h[(size_t)(row0 + r) * SYS + col] = acc[mi][nj][r] + bias;
        }
    }
}

// ---------------------------------------------------------------------------
// GEMM1 fallback (in-kernel conversion, 64x64) — only if workspace too small.
// ---------------------------------------------------------------------------
#define BM2 64
#define BN2 64
#define BK2 32
#define LDK2 40

__global__ __launch_bounds__(256, 4) void gemm1_kernel(
    const float* __restrict__ x, const float* __restrict__ W1,
    const float* __restrict__ b1, float* __restrict__ h)
{
    __shared__ short Ah[BM2 * LDK2], Al[BM2 * LDK2];
    __shared__ short Bh[BN2 * LDK2], Bl[BN2 * LDK2];

    const int t  = threadIdx.x;
    const int bm = blockIdx.y * BM2;
    const int bn = blockIdx.x * BN2;

    const int srow = t >> 2;
    const int kq   = (t & 3) * 8;

    const int wv   = t >> 6;
    const int lane = t & 63;
    const int lm   = lane & 15;
    const int q    = lane >> 4;

    float4v acc[4];
    #pragma unroll
    for (int j = 0; j < 4; ++j) {
        acc[j][0] = 0.f; acc[j][1] = 0.f; acc[j][2] = 0.f; acc[j][3] = 0.f;
    }

    const float* xa0 = x  + (size_t)(bm + srow) * INSZ + kq;
    const float* wb0 = W1 + (size_t)(bn + srow) * INSZ + kq;

    for (int it = 0; it < 25; ++it) {
        const int k0 = it * BK2;
        {
            const bool valid = (k0 + kq) < INSZ;
            float va[8], vb[8];
            if (valid) {
                #pragma unroll
                for (int p = 0; p < 2; ++p) {
                    float4 xv = ((const float4*)(xa0 + k0))[p];
                    float4 bv = ((const float4*)(wb0 + k0))[p];
                    va[4*p+0] = xv.x; va[4*p+1] = xv.y; va[4*p+2] = xv.z; va[4*p+3] = xv.w;
                    vb[4*p+0] = bv.x; vb[4*p+1] = bv.y; vb[4*p+2] = bv.z; vb[4*p+3] = bv.w;
                }
            } else {
                #pragma unroll
                for (int j = 0; j < 8; ++j) { va[j] = 0.f; vb[j] = 0.f; }
            }
            short8 ahi, alo, bhi, blo;
            #pragma unroll
            for (int j = 0; j < 8; ++j) {
                short h1 = f2bf(va[j]);
                short l1 = f2bf(va[j] - bf2f(h1));
                short h2 = f2bf(vb[j]);
                short l2 = f2bf(vb[j] - bf2f(h2));
                ahi[j] = h1;  alo[j] = l1;
                bhi[j] = h2;  blo[j] = l2;
            }
            const int base = srow * LDK2 + kq;
            *(short8*)&Ah[base] = ahi;
            *(short8*)&Al[base] = alo;
            *(short8*)&Bh[base] = bhi;
            *(short8*)&Bl[base] = blo;
        }
        __syncthreads();

        const int aoff = (wv * 16 + lm) * LDK2 + q * 8;
        short8 ah = *(const short8*)&Ah[aoff];
        short8 al = *(const short8*)&Al[aoff];
        #pragma unroll
        for (int fj = 0; fj < 4; ++fj) {
            const int boff = (fj * 16 + lm) * LDK2 + q * 8;
            short8 bh = *(const short8*)&Bh[boff];
            short8 bl = *(const short8*)&Bl[boff];
            acc[fj] = __builtin_amdgcn_mfma_f32_16x16x32_bf16(ah, bh, acc[fj], 0, 0, 0);
            acc[fj] = __builtin_amdgcn_mfma_f32_16x16x32_bf16(ah, bl, acc[fj], 0, 0, 0);
            acc[fj] = __builtin_amdgcn_mfma_f32_16x16x32_bf16(al, bh, acc[fj], 0, 0, 0);
        }
        __syncthreads();
    }

    #pragma unroll
    for (int fj = 0; fj < 4; ++fj) {
        const int col  = bn + fj * 16 + lm;
        const float bias = b1[col];
        const int row0 = bm + wv * 16 + q * 4;
        #pragma unroll
        for (int r = 0; r < 4; ++r)
            h[(size_t)(row0 + r) * SYS + col] = acc[fj][r] + bias;
    }
}

// ---------------------------------------------------------------------------
// RK4 Lorenz-96 + GEMM2 + log_softmax — unchanged (measured VALU roofline:
// ~300 us; VALUBusy ~80%, MfmaUtil 0, HBM ~1%).
// ---------------------------------------------------------------------------
__global__ __launch_bounds__(256, 4) void rk4_kernel(
    const float* __restrict__ hbuf, const float* __restrict__ W2,
    const float* __restrict__ b2, float* __restrict__ out)
{
    const int lane = threadIdx.x & 63;
    const int w    = threadIdx.x >> 6;
    const int rowA = blockIdx.x * 8 + w * 2;
    const int rowB = rowA + 1;

    const int laneL = (lane + 63) & 63;
    const int laneR = (lane + 1) & 63;

    v2f X[16];
    {
        const float4* a4 = (const float4*)(hbuf + (size_t)rowA * SYS) + lane * 4;
        const float4* b4 = (const float4*)(hbuf + (size_t)rowB * SYS) + lane * 4;
        #pragma unroll
        for (int k = 0; k < 4; ++k) {
            float4 av = a4[k], bv = b4[k];
            X[4*k+0] = mk2(av.x, bv.x);
            X[4*k+1] = mk2(av.y, bv.y);
            X[4*k+2] = mk2(av.z, bv.z);
            X[4*k+3] = mk2(av.w, bv.w);
        }
    }

    const v2f Fv     = mk2(FFORCE, FFORCE);
    const v2f c_half = mk2(0.5f * HSTEP, 0.5f * HSTEP);
    const v2f c_full = mk2(HSTEP, HSTEP);
    const v2f c_two  = mk2(2.0f, 2.0f);
    const v2f c_six  = mk2(HSTEP / 6.0f, HSTEP / 6.0f);

    v2f acc[16], T[16];

    auto deriv_ip = [&](v2f (&y)[16], v2f r1, v2f l1, v2f l2) {
        v2f y0o = y[0], y1o = y[1], y2o = y[2];
        v2f d0 = Fv - y[0], d1 = Fv - y[1], d15 = Fv - y[15];
        v2f p2 = y0o, p1 = y1o, cur = y[2];
        #pragma unroll
        for (int i = 2; i < 15; ++i) {
            v2f yp1 = (i < 14) ? y[i + 1] : y[15];
            v2f nv  = pkfma(yp1 - p2, p1, Fv - cur);
            p2 = p1; p1 = cur;
            if (i < 14) cur = y[i + 1];
            y[i] = nv;
        }
        y[15] = pkfma(r1 - p2, p1, d15);
        y[1]  = pkfma(y2o - l1, y0o, d1);
        y[0]  = pkfma(y1o - l2, l1, d0);
    };

    v2f r1x = sh2(X[0],  laneR);
    v2f l1x = sh2(X[15], laneL);
    v2f l2x = sh2(X[14], laneL);

    #pragma unroll 1
    for (int s = 0; s < NSTEP; ++s) {
        #pragma unroll
        for (int i = 2; i < 15; ++i)
            acc[i] = pkfma(X[i + 1] - X[i - 2], X[i - 1], Fv - X[i]);
        acc[15] = pkfma(r1x - X[13], X[14], Fv - X[15]);
        acc[1]  = pkfma(X[2] - l1x, X[0],  Fv - X[1]);
        acc[0]  = pkfma(X[1] - l2x, l1x,   Fv - X[0]);

        T[14] = pkfma(c_half, acc[14], X[14]);
        T[15] = pkfma(c_half, acc[15], X[15]);
        T[0]  = pkfma(c_half, acc[0],  X[0]);
        v2f r1 = sh2(T[0],  laneR);
        v2f l1 = sh2(T[15], laneL);
        v2f l2 = sh2(T[14], laneL);
        #pragma unroll
        for (int i = 1; i < 14; ++i) T[i] = pkfma(c_half, acc[i], X[i]);
        deriv_ip(T, r1, l1, l2);

        {
            v2f a;
            a = T[14]; acc[14] = pkfma(c_two, a, acc[14]); T[14] = pkfma(c_half, a, X[14]);
            a = T[15]; acc[15] = pkfma(c_two, a, acc[15]); T[15] = pkfma(c_half, a, X[15]);
            a = T[0];  acc[0]  = pkfma(c_two, a, acc[0]);  T[0]  = pkfma(c_half, a, X[0]);
            r1 = sh2(T[0],  laneR);
            l1 = sh2(T[15], laneL);
            l2 = sh2(T[14], laneL);
            #pragma unroll
            for (int i = 1; i < 14; ++i) {
                a = T[i]; acc[i] = pkfma(c_two, a, acc[i]); T[i] = pkfma(c_half, a, X[i]);
            }
        }
        deriv_ip(T, r1, l1, l2);

        {
            v2f a;
            a = T[14]; acc[14] = pkfma(c_two, a, acc[14]); T[14] = pkfma(c_full, a, X[14]);
            a = T[15]; acc[15] = pkfma(c_two, a, acc[15]); T[15] = pkfma(c_full, a, X[15]);
            a = T[0];  acc[0]  = pkfma(c_two, a, acc[0]);  T[0]  = pkfma(c_full, a, X[0]);
            r1 = sh2(T[0],  laneR);
            l1 = sh2(T[15], laneL);
            l2 = sh2(T[14], laneL);
            #pragma unroll
            for (int i = 1; i < 14; ++i) {
                a = T[i]; acc[i] = pkfma(c_two, a, acc[i]); T[i] = pkfma(c_full, a, X[i]);
            }
        }
        deriv_ip(T, r1, l1, l2);

        X[14] = pkfma(c_six, acc[14] + T[14], X[14]);
        X[15] = pkfma(c_six, acc[15] + T[15], X[15]);
        X[0]  = pkfma(c_six, acc[0]  + T[0],  X[0]);
        r1x = sh2(X[0],  laneR);
        l1x = sh2(X[15], laneL);
        l2x = sh2(X[14], laneL);
        #pragma unroll
        for (int i = 1; i < 14; ++i)
            X[i] = pkfma(c_six, acc[i] + T[i], X[i]);
    }

    v2f l[OUTSZ];
    #pragma unroll
    for (int o = 0; o < OUTSZ; ++o) {
        const float4* w4 = (const float4*)(W2 + (size_t)o * SYS) + lane * 4;
        v2f s2 = mk2(0.f, 0.f);
        #pragma unroll
        for (int k = 0; k < 4; ++k) {
            float4 wv = w4[k];
            s2 = pkfma(X[4*k+0], mk2(wv.x, wv.x), s2);
            s2 = pkfma(X[4*k+1], mk2(wv.y, wv.y), s2);
            s2 = pkfma(X[4*k+2], mk2(wv.z, wv.z), s2);
            s2 = pkfma(X[4*k+3], mk2(wv.w, wv.w), s2);
        }
        #pragma unroll
        for (int dlt = 1; dlt < 64; dlt <<= 1) {
            s2.x += __shfl_xor(s2.x, dlt);
            s2.y += __shfl_xor(s2.y, dlt);
        }
        const float bo = b2[o];
        l[o] = s2 + mk2(bo, bo);
    }

    v2f m = l[0];
    #pragma unroll
    for (int o = 1; o < OUTSZ; ++o) m = __builtin_elementwise_max(m, l[o]);
    v2f ssum = mk2(0.f, 0.f);
    #pragma unroll
    for (int o = 0; o < OUTSZ; ++o) {
        v2f d = l[o] - m;
        ssum = ssum + mk2(__expf(d.x), __expf(d.y));
    }
    const v2f lse = m + mk2(__logf(ssum.x), __logf(ssum.y));

    float vA = l[0].x - lse.x;
    float vB = l[0].y - lse.y;
    #pragma unroll
    for (int o = 1; o < OUTSZ; ++o) {
        if (lane == o) { vA = l[o].x - lse.x; vB = l[o].y - lse.y; }
    }
    if (lane < OUTSZ) {
        out[(size_t)rowA * OUTSZ + lane] = vA;
        out[(size_t)rowB * OUTSZ + lane] = vB;
    }
}

extern "C" void kernel_launch(void* const* d_in, const int* in_sizes, int n_in,
                              void* d_out, int out_size, void* d_ws, size_t ws_size,
                              hipStream_t stream)
{
    const float* x  = (const float*)d_in[0];
    const float* W1 = (const float*)d_in[1];
    const float* b1 = (const float*)d_in[2];
    const float* W2 = (const float*)d_in[3];
    const float* b2 = (const float*)d_in[4];
    float* out = (float*)d_out;
    float* h   = (float*)d_ws;   // 8192*1024*4 = 33.5 MB scratch

    const size_t hbytes      = (size_t)BATCH * SYS * sizeof(float);
    const size_t splitshorts = (size_t)(BATCH + SYS) * KP;           // per hi/lo member
    const size_t need        = hbytes + 2 * splitshorts * sizeof(short);

    if (ws_size >= need) {
        short* xh = (short*)((char*)d_ws + hbytes);
        short* xl = xh + (size_t)BATCH * KP;
        short* wh = xl + (size_t)BATCH * KP;
        short* wl = wh + (size_t)SYS * KP;
        convert_kernel<<<2048, 256, 0, stream>>>(x, W1, xh, xl, wh, wl);
        dim3 g1(SYS / BN3, BATCH / BM3);   // 8 x 64 = 512 blocks, 512 threads
        gemm1s_kernel<<<g1, 512, 0, stream>>>(xh, xl, wh, wl, b1, h);
    } else {
        dim3 g1(SYS / BN2, BATCH / BM2);   // fallback: 16 x 128 = 2048 blocks
        gemm1_kernel<<<g1, 256, 0, stream>>>(x, W1, b1, h);
    }

    rk4_kernel<<<BATCH / 8, 256, 0, stream>>>(h, W2, b2, out);  // 1024 blocks
}